// Round 6
// baseline (156.512 us; speedup 1.0000x reference)
//
#include <hip/hip_runtime.h>

#define B_    64
#define HW_   196
#define HWP_  224
#define D_    768
#define E_    256
#define C_    10
#define MP_   (B_*HWP_)   // 14336 padded rows
#define K3K_  (E_*D_)     // 196608 deep-K for final contraction
#define K3NB_ 256         // k3 partial blocks (768 k each) -> non-atomic partials

typedef __bf16 bf16x8 __attribute__((ext_vector_type(8)));
typedef __bf16 bf16x4 __attribute__((ext_vector_type(4)));
typedef __bf16 bf16x2 __attribute__((ext_vector_type(2)));
typedef float  f32x4  __attribute__((ext_vector_type(4)));

// async global->LDS, 16B per lane; LDS dest is wave-uniform base + lane*16
__device__ __forceinline__ void gld_lds16(const void* g, void* l) {
  __builtin_amdgcn_global_load_lds((const __attribute__((address_space(1))) void*)g,
                                   (__attribute__((address_space(3))) void*)l, 16, 0, 0);
}

// ---------------- K0prep: merged {ag_w -> bf16 hi/lo} and {lm_w -> W2 permute} --------
__global__ __launch_bounds__(256) void k0_prep(const float* __restrict__ w,
                                               __bf16* __restrict__ whi,
                                               __bf16* __restrict__ wlo,
                                               const float* __restrict__ lmw,
                                               __bf16* __restrict__ w2) {
  int bid = blockIdx.x;
  if (bid < 192) {
    size_t i4 = ((size_t)bid * 256 + threadIdx.x) * 4;
    float4 v = *(const float4*)&w[i4];
    float vv[4] = {v.x, v.y, v.z, v.w};
    bf16x4 h, l;
#pragma unroll
    for (int j = 0; j < 4; j++) {
      __bf16 hj = (__bf16)vv[j];
      float r = vv[j] - (float)hj;
      h[j] = hj;
      l[j] = (__bf16)r;
    }
    *(bf16x4*)&whi[i4] = h;
    *(bf16x4*)&wlo[i4] = l;
  } else {
    size_t i4 = ((size_t)(bid - 192) * 256 + threadIdx.x) * 4;  // < 16*K3K_
    int c = (int)(i4 / K3K_);
    int rem = (int)(i4 - (size_t)c * K3K_);
    int e = rem / D_;
    int d = rem - e * D_;
    bf16x4 o;
    if (c < C_) {
      float4 v = *(const float4*)&lmw[((size_t)e * C_ + c) * D_ + d];
      o[0] = (__bf16)v.x; o[1] = (__bf16)v.y; o[2] = (__bf16)v.z; o[3] = (__bf16)v.w;
    } else {
      o[0] = o[1] = o[2] = o[3] = (__bf16)0.0f;
    }
    *(bf16x4*)&w2[i4] = o;
  }
}

// ---------------- K1: sign GEMM, BM=32 x full-N(256e), 2 blocks/CU co-resident ------
// R5 post-mortem: grid was 224 blocks on 256 CUs (0.875/CU, 80KB LDS) -> one block
// deep, no cross-block latency hiding for cold-x misses. Now BM=32: grid 448,
// LDS 72KB -> 2 blocks/CU; HWP=224=7*32 so each block lies in ONE batch b.
__global__ __launch_bounds__(256) void k1_signs(const float* __restrict__ x,
                                                const __bf16* __restrict__ whi,
                                                const __bf16* __restrict__ wlo,
                                                const float* __restrict__ bias,
                                                __bf16* __restrict__ st) {
  __shared__ __align__(16) char smem[73728];           // 72 KB
  __bf16* Ah = (__bf16*)smem;                          // [2][32*32]   4 KB
  __bf16* Al = (__bf16*)(smem + 4096);                 // [2][32*32]   4 KB
  __bf16* Bh = (__bf16*)(smem + 8192);                 // [2][256*32] 32 KB
  __bf16* Bl = (__bf16*)(smem + 40960);                // [2][256*32] 32 KB
  const int ab  = blockIdx.x / 7;                      // batch (block never straddles)
  const int hp0 = (blockIdx.x % 7) * 32;               // hp base
  const int tid = threadIdx.x;
  const int wave = tid >> 6, lane = tid & 63;
  const int wn = wave * 64;                            // e-offset of this wave
  const int q = lane >> 4, l15 = lane & 15;

  // A staging: thread -> row ar = tid>>3 (0..31), 4 k at acl = (tid&7)*4
  const int ar = tid >> 3;
  const int acl = (tid & 7) * 4;
  const int ahp = hp0 + ar;
  const bool avalid = (ahp < HW_);
  const float* aptr = &x[((size_t)ab * HW_ + (avalid ? ahp : 0)) * D_ + acl];

  // B staging: 4 chunks of 64 rows; thread covers row br_+c*64, 8 k at bc
  const int br_ = tid >> 2;
  const int bc = (tid & 3) * 8;
  const size_t offB = (size_t)br_ * D_ + bc;
  const int ldB = wave * 512;                          // lane-linear dest in chunk

  f32x4 acc[2][4] = {};
  float4 a0;

#define K1_LOADA(kk) do { \
    a0 = avalid ? *(const float4*)&aptr[(kk)] : make_float4(0.f, 0.f, 0.f, 0.f); \
  } while (0)

#define K1_CONVWRITE(buf) do { \
    float va[4] = {a0.x, a0.y, a0.z, a0.w}; \
    bf16x4 hh, ll; \
    _Pragma("unroll") \
    for (int j = 0; j < 4; j++) { \
      __bf16 hj = (__bf16)va[j]; float r = va[j] - (float)hj; \
      hh[j] = hj; ll[j] = (__bf16)r; \
    } \
    *(bf16x4*)&Ah[(buf) * 1024 + ar * 32 + acl] = hh; \
    *(bf16x4*)&Al[(buf) * 1024 + ar * 32 + acl] = ll; \
  } while (0)

#define K1_STAGEB(buf, kk) do { \
    _Pragma("unroll") \
    for (int c = 0; c < 4; c++) { \
      gld_lds16(&whi[offB + (size_t)c * 64 * D_ + (kk)], &Bh[(buf) * 8192 + c * 2048 + ldB]); \
      gld_lds16(&wlo[offB + (size_t)c * 64 * D_ + (kk)], &Bl[(buf) * 8192 + c * 2048 + ldB]); \
    } \
  } while (0)

  // prologue: tile 0
  K1_LOADA(0);
  K1_STAGEB(0, 0);
  K1_CONVWRITE(0);
  __syncthreads();

  int cur = 0;
  for (int k0 = 0; k0 < D_; k0 += 32) {
    const bool have = (k0 + 32 < D_);
    if (have) {
      K1_LOADA(k0 + 32);            // global loads issued early
      K1_STAGEB(cur ^ 1, k0 + 32);  // DMA prefetch
    }
    bf16x8 ah[2], al[2], bh[4], bl[4];
#pragma unroll
    for (int t = 0; t < 2; t++) {
      int ra = cur * 1024 + (t * 16 + l15) * 32 + q * 8;
      ah[t] = *(const bf16x8*)&Ah[ra];
      al[t] = *(const bf16x8*)&Al[ra];
    }
#pragma unroll
    for (int t = 0; t < 4; t++) {
      int rb = cur * 8192 + (wn + t * 16 + l15) * 32 + q * 8;
      bh[t] = *(const bf16x8*)&Bh[rb];
      bl[t] = *(const bf16x8*)&Bl[rb];
    }
#pragma unroll
    for (int mt = 0; mt < 2; mt++)
#pragma unroll
      for (int nt = 0; nt < 4; nt++) {
        acc[mt][nt] = __builtin_amdgcn_mfma_f32_16x16x32_bf16(ah[mt], bh[nt], acc[mt][nt], 0, 0, 0);
        acc[mt][nt] = __builtin_amdgcn_mfma_f32_16x16x32_bf16(al[mt], bh[nt], acc[mt][nt], 0, 0, 0);
        acc[mt][nt] = __builtin_amdgcn_mfma_f32_16x16x32_bf16(ah[mt], bl[nt], acc[mt][nt], 0, 0, 0);
      }
    if (have) K1_CONVWRITE(cur ^ 1);   // vmcnt wait lands here, covered by MFMAs
    __syncthreads();
    cur ^= 1;
  }
#undef K1_LOADA
#undef K1_CONVWRITE
#undef K1_STAGEB

  // ---- epilogue: sign+bias -> LDS transpose Sload[e][m] -> coalesced st writes ----
  __syncthreads();                       // all MFMA-phase LDS reads done; reuse pool
  __bf16* Sload = (__bf16*)smem;         // [256][40] = 20 KB
#pragma unroll
  for (int mt = 0; mt < 2; mt++)
#pragma unroll
    for (int nt = 0; nt < 4; nt++) {
      int e = wn + nt * 16 + l15;
      float bv = bias[e];
      bf16x4 o;
#pragma unroll
      for (int r = 0; r < 4; r++) {
        int mloc = mt * 16 + q * 4 + r;     // C/D: row=quad*4+reg, col=lane&15
        int hp = hp0 + mloc;
        float v = acc[mt][nt][r] + bv;
        o[r] = (hp < HW_ && v > 0.0f) ? (__bf16)1.0f : (__bf16)0.0f;  // zero-pad kept
      }
      *(bf16x4*)&Sload[e * 40 + mt * 16 + q * 4] = o;
    }
  __syncthreads();
#pragma unroll
  for (int it = 0; it < 8; it++) {
    int e = (tid >> 3) + it * 32;
    int m4 = (tid & 7) * 4;
    bf16x4 v = *(const bf16x4*)&Sload[e * 40 + m4];
    *(bf16x4*)&st[((size_t)ab * E_ + e) * HWP_ + hp0 + m4] = v;
  }
}

// ---------------- K2: per-batch G = S^T · X, FULL-M (256 e), XCD-grouped ----------
// Block = (d0, b); 512 threads = 8 waves (4e x 2d). XCD-aware remap: all 6
// d-blocks of a batch b land on the SAME XCD (idx%8 round-robin assumption) ->
// st[b] is fetched into ONE L2, not six (8 b's x 112KB = 896KB/XCD, L2-resident).
__global__ __launch_bounds__(512) void k2_g(const __bf16* __restrict__ st,
                                            const float* __restrict__ x,
                                            __bf16* __restrict__ g) {
  __shared__ __align__(16) __bf16 As[2][256 * 32];   // 32 KB
  __shared__ __align__(16) __bf16 Bs[2][128 * 40];   // 20 KB, Bs[d][k] stride 40
  const int f = blockIdx.x;                // 0..383
  const int xcd = f & 7;
  const int slot = f >> 3;                 // 0..47
  const int b  = xcd + 8 * (slot / 6);
  const int d0 = (slot % 6) * 128;
  const int tid = threadIdx.x;
  const int wave = tid >> 6, lane = tid & 63;
  const int WE = (wave & 3) * 64;          // e-offset
  const int WD = (wave >> 2) * 64;         // d-offset within 128
  const int q = lane >> 4, l15 = lane & 15;
  // A staging: thread -> row ar = tid>>2 (0..127), 8 k at ac = (tid&3)*8; rows ar, ar+128
  const int ar = tid >> 2, ac = (tid & 3) * 8;
  const int ldA = wave * 512;
  // B staging: thread owns 2k x 4d: dg = tid&31 (d = 4*dg), kp = tid>>5 (k = 2*kp)
  const int dg = tid & 31, kp = tid >> 5;
  f32x4 acc[4][4] = {};

  const __bf16* gA = &st[((size_t)b * E_ + ar) * HWP_ + ac];
  const float4 zero4 = make_float4(0.f, 0.f, 0.f, 0.f);
  float4 f0, f1;

#define K2_STAGEA(buf, kk) do { \
    gld_lds16(gA + (kk),                       &As[buf][ldA]); \
    gld_lds16(gA + (size_t)128 * HWP_ + (kk),  &As[buf][4096 + ldA]); \
  } while (0)

#define K2_LOADB(kk) do { \
    int hp0 = (kk) + 2 * kp; \
    const float* bsrc = &x[((size_t)b * HW_ + hp0) * D_ + d0 + 4 * dg]; \
    f0 = (hp0     < HW_) ? *(const float4*)&bsrc[0]  : zero4; \
    f1 = (hp0 + 1 < HW_) ? *(const float4*)&bsrc[D_] : zero4; \
  } while (0)

#define K2_WRITEB(buf) do { \
    float rr0[4] = {f0.x, f0.y, f0.z, f0.w}; \
    float rr1[4] = {f1.x, f1.y, f1.z, f1.w}; \
    _Pragma("unroll") \
    for (int j = 0; j < 4; j++) { \
      bf16x2 o; \
      o[0] = (__bf16)rr0[j]; o[1] = (__bf16)rr1[j]; \
      *(bf16x2*)&Bs[buf][(4 * dg + j) * 40 + 2 * kp] = o; \
    } \
  } while (0)

  // prologue: stage tile 0 fully
  K2_STAGEA(0, 0);
  K2_LOADB(0);
  K2_WRITEB(0);
  __syncthreads();

  int cur = 0;
  for (int k0 = 0; k0 < HWP_; k0 += 32) {
    const bool have = (k0 + 32 < HWP_);
    if (have) {
      K2_STAGEA(cur ^ 1, k0 + 32);
      K2_LOADB(k0 + 32);
    }
    bf16x8 af[4], bfr[4];
#pragma unroll
    for (int t = 0; t < 4; t++) {
      af[t]  = *(const bf16x8*)&As[cur][(WE + t * 16 + l15) * 32 + q * 8];
      bfr[t] = *(const bf16x8*)&Bs[cur][(WD + t * 16 + l15) * 40 + q * 8];
    }
#pragma unroll
    for (int mt = 0; mt < 4; mt++)
#pragma unroll
      for (int nt = 0; nt < 4; nt++)
        acc[mt][nt] = __builtin_amdgcn_mfma_f32_16x16x32_bf16(af[mt], bfr[nt], acc[mt][nt], 0, 0, 0);
    if (have) K2_WRITEB(cur ^ 1);
    __syncthreads();
    cur ^= 1;
  }
#undef K2_STAGEA
#undef K2_LOADB
#undef K2_WRITEB

#pragma unroll
  for (int mt = 0; mt < 4; mt++)
#pragma unroll
    for (int nt = 0; nt < 4; nt++) {
      int d = d0 + WD + nt * 16 + l15;
#pragma unroll
      for (int r = 0; r < 4; r++) {
        int e = WE + mt * 16 + q * 4 + r;
        g[((size_t)b * E_ + e) * D_ + d] = (__bf16)acc[mt][nt][r];
      }
    }
}

// ---------------- K3: partial preds per k-slice (NO global atomics) ----------------
__global__ __launch_bounds__(256) void k3_mfma(const __bf16* __restrict__ g,
                                               const __bf16* __restrict__ w2,
                                               float* __restrict__ part) {
  __shared__ float sp[B_ * C_];
  const int tid = threadIdx.x;
  const int wave = tid >> 6, lane = tid & 63;
  const int q = lane >> 4, l15 = lane & 15;
  const int kbase = blockIdx.x * (K3K_ / K3NB_) + wave * (K3K_ / K3NB_ / 4);  // 768, 192
  f32x4 acc[4] = {};

  for (int i = tid; i < B_ * C_; i += 256) sp[i] = 0.0f;

#pragma unroll
  for (int ks = 0; ks < 6; ks++) {
    int k = kbase + ks * 32 + q * 8;
    bf16x8 bfrag = *(const bf16x8*)&w2[(size_t)l15 * K3K_ + k];
#pragma unroll
    for (int mt = 0; mt < 4; mt++) {
      bf16x8 afrag = *(const bf16x8*)&g[(size_t)(mt * 16 + l15) * K3K_ + k];
      acc[mt] = __builtin_amdgcn_mfma_f32_16x16x32_bf16(afrag, bfrag, acc[mt], 0, 0, 0);
    }
  }
  __syncthreads();
  if (l15 < C_) {
#pragma unroll
    for (int mt = 0; mt < 4; mt++)
#pragma unroll
      for (int r = 0; r < 4; r++) {
        int b = mt * 16 + q * 4 + r;
        atomicAdd(&sp[b * C_ + l15], acc[mt][r]);   // LDS atomics only
      }
  }
  __syncthreads();
  for (int i = tid; i < B_ * C_; i += 256)
    part[(size_t)blockIdx.x * (B_ * C_) + i] = sp[i];
}

// ---------------- K4: reduce 256 partials -> out ----------------
__global__ __launch_bounds__(256) void k4_reduce(const float* __restrict__ part,
                                                 float* __restrict__ out) {
  __shared__ float sp[256];
  const int b = blockIdx.x;
  const int tid = threadIdx.x;
  const int c = tid & 15, g16 = tid >> 4;   // 16 groups x 16 c-slots
  float s = 0.0f;
  if (c < C_) {
#pragma unroll
    for (int j = 0; j < 16; j++)
      s += part[(size_t)(g16 + 16 * j) * (B_ * C_) + b * C_ + c];
  }
  sp[tid] = s;
  __syncthreads();
  if (tid < C_) {
    float t = 0.0f;
#pragma unroll
    for (int j = 0; j < 16; j++) t += sp[j * 16 + tid];
    out[b * C_ + tid] = t * (1.0f / (196.0f * 256.0f));
  }
}

extern "C" void kernel_launch(void* const* d_in, const int* in_sizes, int n_in,
                              void* d_out, int out_size, void* d_ws, size_t ws_size,
                              hipStream_t stream) {
  const float* x    = (const float*)d_in[0];   // (64,196,768)
  const float* ag_w = (const float*)d_in[1];   // (256,768)
  const float* ag_b = (const float*)d_in[2];   // (256,)
  const float* lm_w = (const float*)d_in[3];   // (2560,768)
  float* out = (float*)d_out;                  // (64,10)

  char* ws = (char*)d_ws;
  const size_t W_BYTES  = (size_t)E_ * D_ * 2;
  const size_t ST_BYTES = (size_t)B_ * E_ * HWP_ * 2;
  const size_t G_BYTES  = (size_t)B_ * E_ * D_ * 2;
  const size_t W2_BYTES = (size_t)16 * K3K_ * 2;
  __bf16* whi  = (__bf16*)(ws);
  __bf16* wlo  = (__bf16*)(ws + W_BYTES);
  __bf16* st   = (__bf16*)(ws + 2 * W_BYTES);
  __bf16* gb   = (__bf16*)(ws + 2 * W_BYTES + ST_BYTES);
  __bf16* w2   = (__bf16*)(ws + 2 * W_BYTES + ST_BYTES + G_BYTES);
  float*  part = (float*)(ws + 2 * W_BYTES + ST_BYTES + G_BYTES + W2_BYTES);

  k0_prep<<<dim3(192 + (16 * K3K_) / 4 / 256), dim3(256), 0, stream>>>(ag_w, whi, wlo, lm_w, w2);
  k1_signs<<<dim3(MP_ / 32), dim3(256), 0, stream>>>(x, whi, wlo, ag_b, st);
  k2_g<<<dim3(6 * B_), dim3(512), 0, stream>>>(st, x, gb);
  k3_mfma<<<dim3(K3NB_), dim3(256), 0, stream>>>(gb, w2, part);
  k4_reduce<<<dim3(B_), dim3(256), 0, stream>>>(part, out);
}

// Round 7
// 154.457 us; speedup vs baseline: 1.0133x; 1.0133x over previous
//
#include <hip/hip_runtime.h>

#define B_    64
#define HW_   196
#define HWP_  224
#define D_    768
#define E_    256
#define C_    10
#define MP_   (B_*HWP_)   // 14336 padded rows
#define K3K_  (E_*D_)     // 196608 deep-K for final contraction
#define K3NB_ 256         // k3 partial blocks (768 k each) -> non-atomic partials

typedef __bf16 bf16x8 __attribute__((ext_vector_type(8)));
typedef __bf16 bf16x4 __attribute__((ext_vector_type(4)));
typedef __bf16 bf16x2 __attribute__((ext_vector_type(2)));
typedef float  f32x4  __attribute__((ext_vector_type(4)));

// async global->LDS, 16B per lane; LDS dest is wave-uniform base + lane*16
__device__ __forceinline__ void gld_lds16(const void* g, void* l) {
  __builtin_amdgcn_global_load_lds((const __attribute__((address_space(1))) void*)g,
                                   (__attribute__((address_space(3))) void*)l, 16, 0, 0);
}

// ---------------- K0prep: merged {ag_w -> bf16 hi/lo} and {lm_w -> W2 permute} --------
__global__ __launch_bounds__(256) void k0_prep(const float* __restrict__ w,
                                               __bf16* __restrict__ whi,
                                               __bf16* __restrict__ wlo,
                                               const float* __restrict__ lmw,
                                               __bf16* __restrict__ w2) {
  int bid = blockIdx.x;
  if (bid < 192) {
    size_t i4 = ((size_t)bid * 256 + threadIdx.x) * 4;
    float4 v = *(const float4*)&w[i4];
    float vv[4] = {v.x, v.y, v.z, v.w};
    bf16x4 h, l;
#pragma unroll
    for (int j = 0; j < 4; j++) {
      __bf16 hj = (__bf16)vv[j];
      float r = vv[j] - (float)hj;
      h[j] = hj;
      l[j] = (__bf16)r;
    }
    *(bf16x4*)&whi[i4] = h;
    *(bf16x4*)&wlo[i4] = l;
  } else {
    size_t i4 = ((size_t)(bid - 192) * 256 + threadIdx.x) * 4;  // < 16*K3K_
    int c = (int)(i4 / K3K_);
    int rem = (int)(i4 - (size_t)c * K3K_);
    int e = rem / D_;
    int d = rem - e * D_;
    bf16x4 o;
    if (c < C_) {
      float4 v = *(const float4*)&lmw[((size_t)e * C_ + c) * D_ + d];
      o[0] = (__bf16)v.x; o[1] = (__bf16)v.y; o[2] = (__bf16)v.z; o[3] = (__bf16)v.w;
    } else {
      o[0] = o[1] = o[2] = o[3] = (__bf16)0.0f;
    }
    *(bf16x4*)&w2[i4] = o;
  }
}

// ---------------- K1: sign GEMM, BM=64 x full-N(256e), NO vmcnt drain ----------------
// R1-R6 post-mortem: every k-step's __syncthreads drained vmcnt(0) -> full memory
// latency on the critical path 24x. Now:
//  - B (whi/wlo, L2-resident): per-wave REGISTER double-buffer direct from global;
//    no LDS, no barrier involvement; compiler inserts late per-use vmcnt waits.
//  - A (cold fp32 x): depth-3 pipeline. Loads for tile t+2 issue at top of step t;
//    conv+ds_write at end of step t+1; 2 A-buffers in LDS (stride 40, conflict-free).
//  - Barriers are raw s_barrier + lgkmcnt(0) ONLY (A ds_writes) + sched_barrier.
__global__ __launch_bounds__(256) void k1_signs(const float* __restrict__ x,
                                                const __bf16* __restrict__ whi,
                                                const __bf16* __restrict__ wlo,
                                                const float* __restrict__ bias,
                                                __bf16* __restrict__ st) {
  __shared__ __align__(16) char smem[36864];   // A-bufs 20KB; epilogue Sload 36KB
  __bf16* Ah = (__bf16*)smem;                  // [2][64*40] = 10240 B
  __bf16* Al = (__bf16*)(smem + 10240);        // [2][64*40] = 10240 B
  const int m0 = blockIdx.x * 64;
  const int tid = threadIdx.x;
  const int wave = tid >> 6, lane = tid & 63;
  const int wn = wave * 64;                    // e-offset of this wave
  const int q = lane >> 4, l15 = lane & 15;

  // A staging: thread -> row ar = tid>>2 (0..63), 8 k at ac=(tid&3)*8 (2x float4)
  const int ar = tid >> 2, ac = (tid & 3) * 8;
  const int am = m0 + ar;
  const int ab = am / HWP_;
  const int ahp = am - ab * HWP_;
  const bool avalid = (ahp < HW_);
  const float* aptr = &x[((size_t)ab * HW_ + (avalid ? ahp : 0)) * D_ + ac];

  // B direct-to-reg: lane covers e-row = wn + t*16 + l15, k-slot q*8
  const size_t boff = (size_t)(wn + l15) * D_ + q * 8;

  f32x4 acc[4][4] = {};
  float4 aX0, aX1, aY0, aY1;                   // two in-flight A reg sets
  bf16x8 bh0[4], bl0[4], bh1[4], bl1[4];       // B reg double-buffer

#define K1_LOADA(r0, r1, kk) do { \
    r0 = *(const float4*)&aptr[(kk)]; \
    r1 = *(const float4*)&aptr[(kk) + 4]; \
  } while (0)

#define K1_CONV(buf, r0, r1) do { \
    float va[8] = {r0.x, r0.y, r0.z, r0.w, r1.x, r1.y, r1.z, r1.w}; \
    bf16x8 hh, ll; \
    _Pragma("unroll") \
    for (int j = 0; j < 8; j++) { \
      float vj = avalid ? va[j] : 0.0f; \
      __bf16 hj = (__bf16)vj; float rr = vj - (float)hj; \
      hh[j] = hj; ll[j] = (__bf16)rr; \
    } \
    *(bf16x8*)&Ah[(buf) * 2560 + ar * 40 + ac] = hh; \
    *(bf16x8*)&Al[(buf) * 2560 + ar * 40 + ac] = ll; \
  } while (0)

#define K1_LOADB(bh, bl, kk) do { \
    _Pragma("unroll") \
    for (int t = 0; t < 4; t++) { \
      bh[t] = *(const bf16x8*)&whi[boff + (size_t)t * 16 * D_ + (kk)]; \
      bl[t] = *(const bf16x8*)&wlo[boff + (size_t)t * 16 * D_ + (kk)]; \
    } \
  } while (0)

#define K1_BAR() do { \
    asm volatile("s_waitcnt lgkmcnt(0)" ::: "memory"); \
    __builtin_amdgcn_s_barrier(); \
    __builtin_amdgcn_sched_barrier(0); \
  } while (0)

#define K1_COMPUTE(buf, bh, bl) do { \
    bf16x8 ah[4], al[4]; \
    _Pragma("unroll") \
    for (int t = 0; t < 4; t++) { \
      int ra = (buf) * 2560 + (t * 16 + l15) * 40 + q * 8; \
      ah[t] = *(const bf16x8*)&Ah[ra]; \
      al[t] = *(const bf16x8*)&Al[ra]; \
    } \
    _Pragma("unroll") \
    for (int mt = 0; mt < 4; mt++) \
      _Pragma("unroll") \
      for (int nt = 0; nt < 4; nt++) { \
        acc[mt][nt] = __builtin_amdgcn_mfma_f32_16x16x32_bf16(ah[mt], bh[nt], acc[mt][nt], 0, 0, 0); \
        acc[mt][nt] = __builtin_amdgcn_mfma_f32_16x16x32_bf16(al[mt], bh[nt], acc[mt][nt], 0, 0, 0); \
        acc[mt][nt] = __builtin_amdgcn_mfma_f32_16x16x32_bf16(ah[mt], bl[nt], acc[mt][nt], 0, 0, 0); \
      } \
  } while (0)

  // prologue: A(0), B(0), A(1); convwrite A(0)
  K1_LOADA(aX0, aX1, 0);
  K1_LOADB(bh0, bl0, 0);
  K1_LOADA(aY0, aY1, 32);
  K1_CONV(0, aX0, aX1);
  K1_BAR();

  for (int kb = 0; kb < 24; kb += 2) {
    // even step t=kb: A-buf 0, B set0
    K1_LOADB(bh1, bl1, (kb + 1) * 32);                      // B(t+1) -> regs
    if (kb + 2 < 24) K1_LOADA(aX0, aX1, (kb + 2) * 32);     // A(t+2) issue
    K1_COMPUTE(0, bh0, bl0);
    K1_CONV(1, aY0, aY1);                                   // A(t+1) -> LDS buf1
    K1_BAR();
    // odd step t=kb+1: A-buf 1, B set1
    if (kb + 2 < 24) K1_LOADB(bh0, bl0, (kb + 2) * 32);     // B(t+2)
    if (kb + 3 < 24) K1_LOADA(aY0, aY1, (kb + 3) * 32);     // A(t+3)
    K1_COMPUTE(1, bh1, bl1);
    if (kb + 2 < 24) K1_CONV(0, aX0, aX1);                  // A(t+2) -> LDS buf0
    K1_BAR();
  }
#undef K1_LOADA
#undef K1_CONV
#undef K1_LOADB
#undef K1_BAR
#undef K1_COMPUTE

  // ---- epilogue: sign+bias -> LDS transpose Sload[e][m] -> coalesced st writes ----
  __bf16* Sload = (__bf16*)smem;         // [256][72] = 36 KB (reuses A pool)
#pragma unroll
  for (int mt = 0; mt < 4; mt++)
#pragma unroll
    for (int nt = 0; nt < 4; nt++) {
      int e = wn + nt * 16 + l15;
      float bv = bias[e];
      bf16x4 o;
#pragma unroll
      for (int r = 0; r < 4; r++) {
        int m = m0 + mt * 16 + q * 4 + r;   // C/D: row=quad*4+reg, col=lane&15
        int b = m / HWP_;
        int hp = m - b * HWP_;
        float v = acc[mt][nt][r] + bv;
        o[r] = (hp < HW_ && v > 0.0f) ? (__bf16)1.0f : (__bf16)0.0f;
      }
      *(bf16x4*)&Sload[e * 72 + mt * 16 + q * 4] = o;
    }
  __syncthreads();
#pragma unroll
  for (int it = 0; it < 16; it++) {
    int e = (tid >> 4) + it * 16;
    int m4 = (tid & 15) * 4;
    bf16x4 v = *(const bf16x4*)&Sload[e * 72 + m4];
    int mabs = m0 + m4;                  // 4-run never straddles b (224 % 4 == 0)
    int b = mabs / HWP_;
    int hp = mabs - b * HWP_;
    *(bf16x4*)&st[((size_t)b * E_ + e) * HWP_ + hp] = v;
  }
}

// ---------------- K2: per-batch G = S^T · X, FULL-M (256 e), XCD-grouped ----------
__global__ __launch_bounds__(512) void k2_g(const __bf16* __restrict__ st,
                                            const float* __restrict__ x,
                                            __bf16* __restrict__ g) {
  __shared__ __align__(16) __bf16 As[2][256 * 32];   // 32 KB
  __shared__ __align__(16) __bf16 Bs[2][128 * 40];   // 20 KB, Bs[d][k] stride 40
  const int f = blockIdx.x;                // 0..383
  const int xcd = f & 7;
  const int slot = f >> 3;                 // 0..47
  const int b  = xcd + 8 * (slot / 6);
  const int d0 = (slot % 6) * 128;
  const int tid = threadIdx.x;
  const int wave = tid >> 6, lane = tid & 63;
  const int WE = (wave & 3) * 64;          // e-offset
  const int WD = (wave >> 2) * 64;         // d-offset within 128
  const int q = lane >> 4, l15 = lane & 15;
  const int ar = tid >> 2, ac = (tid & 3) * 8;
  const int ldA = wave * 512;
  const int dg = tid & 31, kp = tid >> 5;
  f32x4 acc[4][4] = {};

  const __bf16* gA = &st[((size_t)b * E_ + ar) * HWP_ + ac];
  const float4 zero4 = make_float4(0.f, 0.f, 0.f, 0.f);
  float4 f0, f1;

#define K2_STAGEA(buf, kk) do { \
    gld_lds16(gA + (kk),                       &As[buf][ldA]); \
    gld_lds16(gA + (size_t)128 * HWP_ + (kk),  &As[buf][4096 + ldA]); \
  } while (0)

#define K2_LOADB(kk) do { \
    int hp0 = (kk) + 2 * kp; \
    const float* bsrc = &x[((size_t)b * HW_ + hp0) * D_ + d0 + 4 * dg]; \
    f0 = (hp0     < HW_) ? *(const float4*)&bsrc[0]  : zero4; \
    f1 = (hp0 + 1 < HW_) ? *(const float4*)&bsrc[D_] : zero4; \
  } while (0)

#define K2_WRITEB(buf) do { \
    float rr0[4] = {f0.x, f0.y, f0.z, f0.w}; \
    float rr1[4] = {f1.x, f1.y, f1.z, f1.w}; \
    _Pragma("unroll") \
    for (int j = 0; j < 4; j++) { \
      bf16x2 o; \
      o[0] = (__bf16)rr0[j]; o[1] = (__bf16)rr1[j]; \
      *(bf16x2*)&Bs[buf][(4 * dg + j) * 40 + 2 * kp] = o; \
    } \
  } while (0)

  K2_STAGEA(0, 0);
  K2_LOADB(0);
  K2_WRITEB(0);
  __syncthreads();

  int cur = 0;
  for (int k0 = 0; k0 < HWP_; k0 += 32) {
    const bool have = (k0 + 32 < HWP_);
    if (have) {
      K2_STAGEA(cur ^ 1, k0 + 32);
      K2_LOADB(k0 + 32);
    }
    bf16x8 af[4], bfr[4];
#pragma unroll
    for (int t = 0; t < 4; t++) {
      af[t]  = *(const bf16x8*)&As[cur][(WE + t * 16 + l15) * 32 + q * 8];
      bfr[t] = *(const bf16x8*)&Bs[cur][(WD + t * 16 + l15) * 40 + q * 8];
    }
#pragma unroll
    for (int mt = 0; mt < 4; mt++)
#pragma unroll
      for (int nt = 0; nt < 4; nt++)
        acc[mt][nt] = __builtin_amdgcn_mfma_f32_16x16x32_bf16(af[mt], bfr[nt], acc[mt][nt], 0, 0, 0);
    if (have) K2_WRITEB(cur ^ 1);
    __syncthreads();
    cur ^= 1;
  }
#undef K2_STAGEA
#undef K2_LOADB
#undef K2_WRITEB

#pragma unroll
  for (int mt = 0; mt < 4; mt++)
#pragma unroll
    for (int nt = 0; nt < 4; nt++) {
      int d = d0 + WD + nt * 16 + l15;
#pragma unroll
      for (int r = 0; r < 4; r++) {
        int e = WE + mt * 16 + q * 4 + r;
        g[((size_t)b * E_ + e) * D_ + d] = (__bf16)acc[mt][nt][r];
      }
    }
}

// ---------------- K3: partial preds per k-slice (NO global atomics) ----------------
__global__ __launch_bounds__(256) void k3_mfma(const __bf16* __restrict__ g,
                                               const __bf16* __restrict__ w2,
                                               float* __restrict__ part) {
  __shared__ float sp[B_ * C_];
  const int tid = threadIdx.x;
  const int wave = tid >> 6, lane = tid & 63;
  const int q = lane >> 4, l15 = lane & 15;
  const int kbase = blockIdx.x * (K3K_ / K3NB_) + wave * (K3K_ / K3NB_ / 4);  // 768, 192
  f32x4 acc[4] = {};

  for (int i = tid; i < B_ * C_; i += 256) sp[i] = 0.0f;

#pragma unroll
  for (int ks = 0; ks < 6; ks++) {
    int k = kbase + ks * 32 + q * 8;
    bf16x8 bfrag = *(const bf16x8*)&w2[(size_t)l15 * K3K_ + k];
#pragma unroll
    for (int mt = 0; mt < 4; mt++) {
      bf16x8 afrag = *(const bf16x8*)&g[(size_t)(mt * 16 + l15) * K3K_ + k];
      acc[mt] = __builtin_amdgcn_mfma_f32_16x16x32_bf16(afrag, bfrag, acc[mt], 0, 0, 0);
    }
  }
  __syncthreads();
  if (l15 < C_) {
#pragma unroll
    for (int mt = 0; mt < 4; mt++)
#pragma unroll
      for (int r = 0; r < 4; r++) {
        int b = mt * 16 + q * 4 + r;
        atomicAdd(&sp[b * C_ + l15], acc[mt][r]);   // LDS atomics only
      }
  }
  __syncthreads();
  for (int i = tid; i < B_ * C_; i += 256)
    part[(size_t)blockIdx.x * (B_ * C_) + i] = sp[i];
}

// ---------------- K4: reduce 256 partials -> out ----------------
__global__ __launch_bounds__(256) void k4_reduce(const float* __restrict__ part,
                                                 float* __restrict__ out) {
  __shared__ float sp[256];
  const int b = blockIdx.x;
  const int tid = threadIdx.x;
  const int c = tid & 15, g16 = tid >> 4;   // 16 groups x 16 c-slots
  float s = 0.0f;
  if (c < C_) {
#pragma unroll
    for (int j = 0; j < 16; j++)
      s += part[(size_t)(g16 + 16 * j) * (B_ * C_) + b * C_ + c];
  }
  sp[tid] = s;
  __syncthreads();
  if (tid < C_) {
    float t = 0.0f;
#pragma unroll
    for (int j = 0; j < 16; j++) t += sp[j * 16 + tid];
    out[b * C_ + tid] = t * (1.0f / (196.0f * 256.0f));
  }
}

extern "C" void kernel_launch(void* const* d_in, const int* in_sizes, int n_in,
                              void* d_out, int out_size, void* d_ws, size_t ws_size,
                              hipStream_t stream) {
  const float* x    = (const float*)d_in[0];   // (64,196,768)
  const float* ag_w = (const float*)d_in[1];   // (256,768)
  const float* ag_b = (const float*)d_in[2];   // (256,)
  const float* lm_w = (const float*)d_in[3];   // (2560,768)
  float* out = (float*)d_out;                  // (64,10)

  char* ws = (char*)d_ws;
  const size_t W_BYTES  = (size_t)E_ * D_ * 2;
  const size_t ST_BYTES = (size_t)B_ * E_ * HWP_ * 2;
  const size_t G_BYTES  = (size_t)B_ * E_ * D_ * 2;
  const size_t W2_BYTES = (size_t)16 * K3K_ * 2;
  __bf16* whi  = (__bf16*)(ws);
  __bf16* wlo  = (__bf16*)(ws + W_BYTES);
  __bf16* st   = (__bf16*)(ws + 2 * W_BYTES);
  __bf16* gb   = (__bf16*)(ws + 2 * W_BYTES + ST_BYTES);
  __bf16* w2   = (__bf16*)(ws + 2 * W_BYTES + ST_BYTES + G_BYTES);
  float*  part = (float*)(ws + 2 * W_BYTES + ST_BYTES + G_BYTES + W2_BYTES);

  k0_prep<<<dim3(192 + (16 * K3K_) / 4 / 256), dim3(256), 0, stream>>>(ag_w, whi, wlo, lm_w, w2);
  k1_signs<<<dim3(MP_ / 64), dim3(256), 0, stream>>>(x, whi, wlo, ag_b, st);
  k2_g<<<dim3(6 * B_), dim3(512), 0, stream>>>(st, x, gb);
  k3_mfma<<<dim3(K3NB_), dim3(256), 0, stream>>>(gb, w2, part);
  k4_reduce<<<dim3(B_), dim3(256), 0, stream>>>(part, out);
}

// Round 8
// 148.133 us; speedup vs baseline: 1.0566x; 1.0427x over previous
//
#include <hip/hip_runtime.h>

#define B_    64
#define HW_   196
#define HWP_  224
#define D_    768
#define E_    256
#define C_    10
#define MP_   (B_*HWP_)   // 14336 padded rows
#define K3K_  (E_*D_)     // 196608 deep-K for final contraction
#define K3NB_ 256         // k3 partial blocks (768 k each = one e per block)

typedef __bf16 bf16x8 __attribute__((ext_vector_type(8)));
typedef __bf16 bf16x4 __attribute__((ext_vector_type(4)));
typedef __bf16 bf16x2 __attribute__((ext_vector_type(2)));
typedef float  f32x4  __attribute__((ext_vector_type(4)));

// async global->LDS, 16B per lane; LDS dest is wave-uniform base + lane*16
__device__ __forceinline__ void gld_lds16(const void* g, void* l) {
  __builtin_amdgcn_global_load_lds((const __attribute__((address_space(1))) void*)g,
                                   (__attribute__((address_space(3))) void*)l, 16, 0, 0);
}

// ---------------- K0prep: ag_w -> bf16 hi/lo only (w2 permute ELIMINATED) ----------
__global__ __launch_bounds__(256) void k0_prep(const float* __restrict__ w,
                                               __bf16* __restrict__ whi,
                                               __bf16* __restrict__ wlo) {
  size_t i4 = ((size_t)blockIdx.x * 256 + threadIdx.x) * 4;
  float4 v = *(const float4*)&w[i4];
  float vv[4] = {v.x, v.y, v.z, v.w};
  bf16x4 h, l;
#pragma unroll
  for (int j = 0; j < 4; j++) {
    __bf16 hj = (__bf16)vv[j];
    float r = vv[j] - (float)hj;
    h[j] = hj;
    l[j] = (__bf16)r;
  }
  *(bf16x4*)&whi[i4] = h;
  *(bf16x4*)&wlo[i4] = l;
}

// ---------------- K1: sign GEMM, depth-2 pipeline, drain-free barriers -------------
// B (whi/wlo): TRIPLE-buffered LDS via gld_lds DMA, issued 2 steps ahead.
// A (fp32 x): reg-staged depth-2, conv+ds_write after MFMA block (T14).
// Ordering invariant: per step, DMA(t+2) issues BEFORE A-loads(t+2) (sched_barrier
// pinned). vmcnt retires in order, so the compiler's automatic wait for the A(t+1)
// regs (at the conv) retires DMA(t+1) -- DMA(t+2)/A(t+2) stay in flight across the
// raw s_barrier+lgkmcnt(0). No vmcnt(0) drain anywhere in the loop.
__global__ __launch_bounds__(256) void k1_signs(const float* __restrict__ x,
                                                const __bf16* __restrict__ whi,
                                                const __bf16* __restrict__ wlo,
                                                const float* __restrict__ bias,
                                                __bf16* __restrict__ st) {
  __shared__ __align__(16) char smem[118784];  // B 3x32KB = 96KB | A 2x10KB = 20KB
  const int m0 = blockIdx.x * 64;
  const int tid = threadIdx.x;
  const int wave = tid >> 6, lane = tid & 63;
  const int wn = wave * 64;                    // e-offset of this wave
  const int q = lane >> 4, l15 = lane & 15;
  const int swq = (q ^ ((l15 >> 1) & 3)) * 8;  // B read-side swizzled k-col

  // A staging: thread -> row ar = tid>>2 (0..63), 8 k at ac=(tid&3)*8 (2x float4)
  const int ar = tid >> 2, ac = (tid & 3) * 8;
  const int am = m0 + ar;
  const int ab = am / HWP_;
  const int ahp = am - ab * HWP_;
  const bool avalid = (ahp < HW_);
  const float* aptr = &x[((size_t)ab * HW_ + (avalid ? ahp : 0)) * D_ + ac];

  // B DMA: thread covers row (c*64 + tid>>2) at swizzled col, chunks c=0..3
  const int swB = ((tid & 3) ^ ((tid >> 3) & 3)) * 8;   // source-side swizzle
  const size_t offB = (size_t)(tid >> 2) * D_ + swB;

  f32x4 acc[4][4] = {};
  float4 aX0, aX1, aY0, aY1;                   // A reg sets: X = even tiles, Y = odd

#define K1_LOADA(r0, r1, kk) do { \
    r0 = *(const float4*)&aptr[(kk)]; \
    r1 = *(const float4*)&aptr[(kk) + 4]; \
  } while (0)

#define K1_CONV(bufA, r0, r1) do { \
    __bf16* AhW = (__bf16*)(smem + 98304 + (bufA) * 10240); \
    __bf16* AlW = AhW + 2560; \
    float va[8] = {r0.x, r0.y, r0.z, r0.w, r1.x, r1.y, r1.z, r1.w}; \
    bf16x8 hh, ll; \
    _Pragma("unroll") \
    for (int j = 0; j < 8; j++) { \
      float vj = avalid ? va[j] : 0.0f; \
      __bf16 hj = (__bf16)vj; float rr = vj - (float)hj; \
      hh[j] = hj; ll[j] = (__bf16)rr; \
    } \
    *(bf16x8*)&AhW[ar * 40 + ac] = hh; \
    *(bf16x8*)&AlW[ar * 40 + ac] = ll; \
  } while (0)

#define K1_DMAB(buf3, kk) do { \
    char* bb = smem + (buf3) * 32768; \
    _Pragma("unroll") \
    for (int c = 0; c < 4; c++) { \
      gld_lds16(&whi[offB + (size_t)c * 64 * D_ + (kk)], bb + c * 4096 + wave * 1024); \
      gld_lds16(&wlo[offB + (size_t)c * 64 * D_ + (kk)], bb + 16384 + c * 4096 + wave * 1024); \
    } \
  } while (0)

#define K1_COMPUTE(buf3, bufA) do { \
    const __bf16* BhL = (const __bf16*)(smem + (buf3) * 32768); \
    const __bf16* BlL = BhL + 8192; \
    const __bf16* AhL = (const __bf16*)(smem + 98304 + (bufA) * 10240); \
    const __bf16* AlL = AhL + 2560; \
    bf16x8 ah[4], al[4], bh[4], bl[4]; \
    _Pragma("unroll") \
    for (int t = 0; t < 4; t++) { \
      int ra = (t * 16 + l15) * 40 + q * 8; \
      int rb = (wn + t * 16 + l15) * 32 + swq; \
      ah[t] = *(const bf16x8*)&AhL[ra]; \
      al[t] = *(const bf16x8*)&AlL[ra]; \
      bh[t] = *(const bf16x8*)&BhL[rb]; \
      bl[t] = *(const bf16x8*)&BlL[rb]; \
    } \
    __builtin_amdgcn_s_setprio(1); \
    _Pragma("unroll") \
    for (int mt = 0; mt < 4; mt++) \
      _Pragma("unroll") \
      for (int nt = 0; nt < 4; nt++) { \
        acc[mt][nt] = __builtin_amdgcn_mfma_f32_16x16x32_bf16(ah[mt], bh[nt], acc[mt][nt], 0, 0, 0); \
        acc[mt][nt] = __builtin_amdgcn_mfma_f32_16x16x32_bf16(al[mt], bh[nt], acc[mt][nt], 0, 0, 0); \
        acc[mt][nt] = __builtin_amdgcn_mfma_f32_16x16x32_bf16(ah[mt], bl[nt], acc[mt][nt], 0, 0, 0); \
      } \
    __builtin_amdgcn_s_setprio(0); \
  } while (0)

#define K1_BAR() do { \
    asm volatile("s_waitcnt lgkmcnt(0)" ::: "memory"); \
    __builtin_amdgcn_s_barrier(); \
    __builtin_amdgcn_sched_barrier(0); \
  } while (0)

  // prologue: DMA(0), A(0), DMA(1), A(1) in this vmcnt order; conv A(0) drains DMA(0)
  K1_DMAB(0, 0);
  __builtin_amdgcn_sched_barrier(0);
  K1_LOADA(aX0, aX1, 0);
  __builtin_amdgcn_sched_barrier(0);
  K1_DMAB(1, 32);
  __builtin_amdgcn_sched_barrier(0);
  K1_LOADA(aY0, aY1, 32);
  K1_CONV(0, aX0, aX1);
  K1_BAR();

  // main: t = 0..21 (issue t+2, conv t+1)
#pragma unroll
  for (int t = 0; t < 22; ++t) {
    K1_DMAB((t + 2) % 3, (t + 2) * 32);
    __builtin_amdgcn_sched_barrier(0);
    if ((t & 1) == 0) K1_LOADA(aX0, aX1, (t + 2) * 32);
    else              K1_LOADA(aY0, aY1, (t + 2) * 32);
    K1_COMPUTE(t % 3, t & 1);
    if ((t & 1) == 0) K1_CONV(1, aY0, aY1);
    else              K1_CONV(0, aX0, aX1);
    K1_BAR();
  }
  // t = 22: no issue; conv A(23)
  K1_COMPUTE(22 % 3, 0);
  K1_CONV(1, aY0, aY1);
  K1_BAR();
  // t = 23: compute only
  K1_COMPUTE(23 % 3, 1);
  K1_BAR();

#undef K1_LOADA
#undef K1_CONV
#undef K1_DMAB
#undef K1_COMPUTE
#undef K1_BAR

  // ---- epilogue: sign+bias -> LDS transpose Sload[e][m] -> coalesced st writes ----
  __bf16* Sload = (__bf16*)smem;         // [256][72] = 36 KB (reuses pipeline pool)
#pragma unroll
  for (int mt = 0; mt < 4; mt++)
#pragma unroll
    for (int nt = 0; nt < 4; nt++) {
      int e = wn + nt * 16 + l15;
      float bv = bias[e];
      bf16x4 o;
#pragma unroll
      for (int r = 0; r < 4; r++) {
        int m = m0 + mt * 16 + q * 4 + r;   // C/D: row=quad*4+reg, col=lane&15
        int b = m / HWP_;
        int hp = m - b * HWP_;
        float v = acc[mt][nt][r] + bv;
        o[r] = (hp < HW_ && v > 0.0f) ? (__bf16)1.0f : (__bf16)0.0f;
      }
      *(bf16x4*)&Sload[e * 72 + mt * 16 + q * 4] = o;
    }
  __syncthreads();
#pragma unroll
  for (int it = 0; it < 16; it++) {
    int e = (tid >> 4) + it * 16;
    int m4 = (tid & 15) * 4;
    bf16x4 v = *(const bf16x4*)&Sload[e * 72 + m4];
    int mabs = m0 + m4;                  // 4-run never straddles b (224 % 4 == 0)
    int b = mabs / HWP_;
    int hp = mabs - b * HWP_;
    *(bf16x4*)&st[((size_t)b * E_ + e) * HWP_ + hp] = v;
  }
}

// ---------------- K2: per-batch G = S^T · X, FULL-M (256 e), XCD-grouped ----------
__global__ __launch_bounds__(512) void k2_g(const __bf16* __restrict__ st,
                                            const float* __restrict__ x,
                                            __bf16* __restrict__ g) {
  __shared__ __align__(16) __bf16 As[2][256 * 32];   // 32 KB
  __shared__ __align__(16) __bf16 Bs[2][128 * 40];   // 20 KB, Bs[d][k] stride 40
  const int f = blockIdx.x;                // 0..383
  const int xcd = f & 7;
  const int slot = f >> 3;                 // 0..47
  const int b  = xcd + 8 * (slot / 6);
  const int d0 = (slot % 6) * 128;
  const int tid = threadIdx.x;
  const int wave = tid >> 6, lane = tid & 63;
  const int WE = (wave & 3) * 64;          // e-offset
  const int WD = (wave >> 2) * 64;         // d-offset within 128
  const int q = lane >> 4, l15 = lane & 15;
  const int ar = tid >> 2, ac = (tid & 3) * 8;
  const int ldA = wave * 512;
  const int dg = tid & 31, kp = tid >> 5;
  f32x4 acc[4][4] = {};

  const __bf16* gA = &st[((size_t)b * E_ + ar) * HWP_ + ac];
  const float4 zero4 = make_float4(0.f, 0.f, 0.f, 0.f);
  float4 f0, f1;

#define K2_STAGEA(buf, kk) do { \
    gld_lds16(gA + (kk),                       &As[buf][ldA]); \
    gld_lds16(gA + (size_t)128 * HWP_ + (kk),  &As[buf][4096 + ldA]); \
  } while (0)

#define K2_LOADB(kk) do { \
    int hp0 = (kk) + 2 * kp; \
    const float* bsrc = &x[((size_t)b * HW_ + hp0) * D_ + d0 + 4 * dg]; \
    f0 = (hp0     < HW_) ? *(const float4*)&bsrc[0]  : zero4; \
    f1 = (hp0 + 1 < HW_) ? *(const float4*)&bsrc[D_] : zero4; \
  } while (0)

#define K2_WRITEB(buf) do { \
    float rr0[4] = {f0.x, f0.y, f0.z, f0.w}; \
    float rr1[4] = {f1.x, f1.y, f1.z, f1.w}; \
    _Pragma("unroll") \
    for (int j = 0; j < 4; j++) { \
      bf16x2 o; \
      o[0] = (__bf16)rr0[j]; o[1] = (__bf16)rr1[j]; \
      *(bf16x2*)&Bs[buf][(4 * dg + j) * 40 + 2 * kp] = o; \
    } \
  } while (0)

  K2_STAGEA(0, 0);
  K2_LOADB(0);
  K2_WRITEB(0);
  __syncthreads();

  int cur = 0;
  for (int k0 = 0; k0 < HWP_; k0 += 32) {
    const bool have = (k0 + 32 < HWP_);
    if (have) {
      K2_STAGEA(cur ^ 1, k0 + 32);
      K2_LOADB(k0 + 32);
    }
    bf16x8 af[4], bfr[4];
#pragma unroll
    for (int t = 0; t < 4; t++) {
      af[t]  = *(const bf16x8*)&As[cur][(WE + t * 16 + l15) * 32 + q * 8];
      bfr[t] = *(const bf16x8*)&Bs[cur][(WD + t * 16 + l15) * 40 + q * 8];
    }
#pragma unroll
    for (int mt = 0; mt < 4; mt++)
#pragma unroll
      for (int nt = 0; nt < 4; nt++)
        acc[mt][nt] = __builtin_amdgcn_mfma_f32_16x16x32_bf16(af[mt], bfr[nt], acc[mt][nt], 0, 0, 0);
    if (have) K2_WRITEB(cur ^ 1);
    __syncthreads();
    cur ^= 1;
  }
#undef K2_STAGEA
#undef K2_LOADB
#undef K2_WRITEB

#pragma unroll
  for (int mt = 0; mt < 4; mt++)
#pragma unroll
    for (int nt = 0; nt < 4; nt++) {
      int d = d0 + WD + nt * 16 + l15;
#pragma unroll
      for (int r = 0; r < 4; r++) {
        int e = WE + mt * 16 + q * 4 + r;
        g[((size_t)b * E_ + e) * D_ + d] = (__bf16)acc[mt][nt][r];
      }
    }
}

// ---------------- K3: partials, lm_w converted ON THE FLY (w2 eliminated) ----------
// Block i covers k in [768i, 768(i+1)) = exactly e = i. B element (c,k) =
// lm_w[(e*10+c)*768 + d], contiguous in d -> 2x float4 + cvt per fragment.
__global__ __launch_bounds__(256) void k3_mfma(const __bf16* __restrict__ g,
                                               const float* __restrict__ lmw,
                                               float* __restrict__ part) {
  __shared__ float sp[B_ * C_];
  const int tid = threadIdx.x;
  const int wave = tid >> 6, lane = tid & 63;
  const int q = lane >> 4, l15 = lane & 15;
  const int e = blockIdx.x;                 // 0..255
  f32x4 acc[4] = {};

  for (int i = tid; i < B_ * C_; i += 256) sp[i] = 0.0f;

#pragma unroll
  for (int ks = 0; ks < 6; ks++) {
    int d = wave * 192 + ks * 32 + q * 8;
    size_t k = (size_t)e * D_ + d;
    bf16x8 bfrag;
    if (l15 < C_) {
      const float* bp = &lmw[((size_t)e * C_ + l15) * D_ + d];
      float4 b0 = *(const float4*)&bp[0];
      float4 b1 = *(const float4*)&bp[4];
      float bb[8] = {b0.x, b0.y, b0.z, b0.w, b1.x, b1.y, b1.z, b1.w};
#pragma unroll
      for (int j = 0; j < 8; j++) bfrag[j] = (__bf16)bb[j];
    } else {
#pragma unroll
      for (int j = 0; j < 8; j++) bfrag[j] = (__bf16)0.0f;
    }
#pragma unroll
    for (int mt = 0; mt < 4; mt++) {
      bf16x8 afrag = *(const bf16x8*)&g[(size_t)(mt * 16 + l15) * K3K_ + k];
      acc[mt] = __builtin_amdgcn_mfma_f32_16x16x32_bf16(afrag, bfrag, acc[mt], 0, 0, 0);
    }
  }
  __syncthreads();
  if (l15 < C_) {
#pragma unroll
    for (int mt = 0; mt < 4; mt++)
#pragma unroll
      for (int r = 0; r < 4; r++) {
        int b = mt * 16 + q * 4 + r;
        atomicAdd(&sp[b * C_ + l15], acc[mt][r]);   // LDS atomics only
      }
  }
  __syncthreads();
  for (int i = tid; i < B_ * C_; i += 256)
    part[(size_t)blockIdx.x * (B_ * C_) + i] = sp[i];
}

// ---------------- K4: reduce 256 partials -> out ----------------
__global__ __launch_bounds__(256) void k4_reduce(const float* __restrict__ part,
                                                 float* __restrict__ out) {
  __shared__ float sp[256];
  const int b = blockIdx.x;
  const int tid = threadIdx.x;
  const int c = tid & 15, g16 = tid >> 4;   // 16 groups x 16 c-slots
  float s = 0.0f;
  if (c < C_) {
#pragma unroll
    for (int j = 0; j < 16; j++)
      s += part[(size_t)(g16 + 16 * j) * (B_ * C_) + b * C_ + c];
  }
  sp[tid] = s;
  __syncthreads();
  if (tid < C_) {
    float t = 0.0f;
#pragma unroll
    for (int j = 0; j < 16; j++) t += sp[j * 16 + tid];
    out[b * C_ + tid] = t * (1.0f / (196.0f * 256.0f));
  }
}

extern "C" void kernel_launch(void* const* d_in, const int* in_sizes, int n_in,
                              void* d_out, int out_size, void* d_ws, size_t ws_size,
                              hipStream_t stream) {
  const float* x    = (const float*)d_in[0];   // (64,196,768)
  const float* ag_w = (const float*)d_in[1];   // (256,768)
  const float* ag_b = (const float*)d_in[2];   // (256,)
  const float* lm_w = (const float*)d_in[3];   // (2560,768)
  float* out = (float*)d_out;                  // (64,10)

  char* ws = (char*)d_ws;
  const size_t W_BYTES  = (size_t)E_ * D_ * 2;
  const size_t ST_BYTES = (size_t)B_ * E_ * HWP_ * 2;
  const size_t G_BYTES  = (size_t)B_ * E_ * D_ * 2;
  __bf16* whi  = (__bf16*)(ws);
  __bf16* wlo  = (__bf16*)(ws + W_BYTES);
  __bf16* st   = (__bf16*)(ws + 2 * W_BYTES);
  __bf16* gb   = (__bf16*)(ws + 2 * W_BYTES + ST_BYTES);
  float*  part = (float*)(ws + 2 * W_BYTES + ST_BYTES + G_BYTES);

  k0_prep<<<dim3(192), dim3(256), 0, stream>>>(ag_w, whi, wlo);
  k1_signs<<<dim3(MP_ / 64), dim3(256), 0, stream>>>(x, whi, wlo, ag_b, st);
  k2_g<<<dim3(6 * B_), dim3(512), 0, stream>>>(st, x, gb);
  k3_mfma<<<dim3(K3NB_), dim3(256), 0, stream>>>(gb, lm_w, part);
  k4_reduce<<<dim3(B_), dim3(256), 0, stream>>>(part, out);
}